// Round 12
// baseline (807.702 us; speedup 1.0000x reference)
//
#include <hip/hip_runtime.h>
#include <hip/hip_bf16.h>

typedef unsigned short u16;
typedef __attribute__((ext_vector_type(8))) short short8;
typedef __attribute__((ext_vector_type(4))) float f32x4;
typedef const __attribute__((address_space(1))) void GV;
typedef __attribute__((address_space(3))) void LV;
#define GLOAD16(g, l) __builtin_amdgcn_global_load_lds((GV*)(g), (LV*)(l), 16, 0, 0)
#define BAR() asm volatile("s_barrier" ::: "memory")

#define BATCH 512
#define LSEQ  64
#define EMB   1024
#define NH    16
#define NQKV  3328              // 1024 q | 1024 k | 1024 v | 32 sc | 224 pad (multiple of 256)
#define MROWS (BATCH*LSEQ)      // 32768

__device__ __forceinline__ u16 f2b(float f){
  __hip_bfloat16 h = __float2bfloat16(f);
  return *reinterpret_cast<u16*>(&h);
}
__device__ __forceinline__ float b2f(u16 u){
  return __uint_as_float(((unsigned)u) << 16);
}
__device__ __forceinline__ uint2 pack4(float4 v){
  unsigned lo = (unsigned)f2b(v.x) | ((unsigned)f2b(v.y) << 16);
  unsigned hi = (unsigned)f2b(v.z) | ((unsigned)f2b(v.w) << 16);
  return make_uint2(lo, hi);
}

// ---------------------------------------------------------------- fused prep
// One kernel, block-range sections (confirmed −94us vs 9 launches, R5).
// Added: bf16 conversions of sh1_w / sg_w for the fused smolgen kernel.
__device__ __forceinline__ void tpose(const float* __restrict__ src, u16* __restrict__ dst,
                                      int K, int N, int dstLd, int dstRowOff,
                                      int blk, int tid, float (*t)[33]){
  int nbx = N >> 5;
  int bx = blk % nbx, by = blk / nbx;
  int n0 = bx << 5, k0 = by << 5;
  int lx = tid & 31, ly = tid >> 5;   // 32 x 8
  #pragma unroll
  for (int i = 0; i < 32; i += 8)
    t[ly + i][lx] = src[(size_t)(k0 + ly + i) * N + n0 + lx];
  __syncthreads();
  #pragma unroll
  for (int i = 0; i < 32; i += 8)
    dst[(size_t)(dstRowOff + n0 + ly + i) * dstLd + k0 + lx] = f2b(t[lx][ly + i]);
}

#define PREP_BLOCKS 39693
__global__ __launch_bounds__(256) void prep_all(const float* __restrict__ x, u16* __restrict__ xb,
                                                const float* __restrict__ wq, const float* __restrict__ wk,
                                                const float* __restrict__ wv, const float* __restrict__ sc_w,
                                                const float* __restrict__ wo, const float* __restrict__ swg_w,
                                                u16* __restrict__ wqkvT, u16* __restrict__ woT,
                                                u16* __restrict__ swgT,
                                                const float* __restrict__ bq, const float* __restrict__ bk,
                                                const float* __restrict__ bv, float* __restrict__ qbias,
                                                const float* __restrict__ sh1_w, u16* __restrict__ sh1_wb,
                                                const float* __restrict__ sg_w,  u16* __restrict__ sg_wb){
  __shared__ float t[32][33];
  const int blk = blockIdx.x, tid = threadIdx.x;
  if (blk < 32768){
    size_t i = ((size_t)blk * 256 + tid) * 4;
    float4 v = *(const float4*)&x[i];
    *(uint2*)&xb[i] = pack4(v);
  } else if (blk < 33792){
    tpose(wq,   wqkvT, 1024, 1024, 1024, 0,    blk - 32768, tid, t);
  } else if (blk < 34816){
    tpose(wk,   wqkvT, 1024, 1024, 1024, 1024, blk - 33792, tid, t);
  } else if (blk < 35840){
    tpose(wv,   wqkvT, 1024, 1024, 1024, 2048, blk - 34816, tid, t);
  } else if (blk < 35872){
    tpose(sc_w, wqkvT, 1024, 32,   1024, 3072, blk - 35840, tid, t);
  } else if (blk < 36896){
    tpose(wo,   woT,   1024, 1024, 1024, 0,    blk - 35872, tid, t);
  } else if (blk < 37920){
    tpose(swg_w, swgT, 256,  4096, 256,  0,    blk - 36896, tid, t);
  } else if (blk < 38144){
    size_t i = (size_t)(blk - 37920) * 1024 + tid * 4;
    *(uint2*)&wqkvT[(size_t)3104 * 1024 + i] = make_uint2(0, 0);
  } else if (blk < 38157){
    int i = (blk - 38144) * 256 + tid;
    if (i < NQKV){
      float v = 0.f;
      if (i < 1024) v = bq[i];
      else if (i < 2048) v = bk[i - 1024];
      else if (i < 3072) v = bv[i - 2048];
      qbias[i] = v;
    }
  } else if (blk < 38669){
    size_t i = (size_t)(blk - 38157) * 1024 + tid * 4;
    *(uint2*)&sh1_wb[i] = pack4(*(const float4*)&sh1_w[i]);
  } else {
    size_t i = (size_t)(blk - 38669) * 1024 + tid * 4;
    *(uint2*)&sg_wb[i] = pack4(*(const float4*)&sg_w[i]);
  }
}

// ---------------------------------------------------------------- 256x256 8-phase GEMM
// (R2/R5/R10-known-good schedule: QKV 267us, MfmaUtil 36%, 0 bank conflicts —
// DO NOT touch the phase structure; two balancing experiments both regressed.)
template<int OUT_BF16, int HAS_BIAS>
__global__ __launch_bounds__(512, 2) void gemm256(const u16* __restrict__ A,
                                                  const u16* __restrict__ Bt,
                                                  const float* __restrict__ bias,
                                                  void* __restrict__ Cv,
                                                  int M, int N, int K){
  __shared__ u16 lA[2][16384];   // [buf][half*8192 + row*64 + swz_slot*8]
  __shared__ u16 lB[2][16384];
  const int ntn = N >> 8;
  const int nwg = gridDim.x, bid = blockIdx.x;
  const int qq = nwg >> 3, r8 = nwg & 7, xcd = bid & 7, kk = bid >> 3;
  const int wg = (xcd < r8 ? xcd * (qq + 1) : r8 * (qq + 1) + (xcd - r8) * qq) + kk;
  const int tm = wg / ntn, tn = wg % ntn;
  const int m0 = tm << 8, n0 = tn << 8;
  const int tid = threadIdx.x;
  const int w = tid >> 6, lane = tid & 63;
  const int wm = w >> 2, wn = w & 3;
  const int l15 = lane & 15, l4 = lane >> 4;

  size_t ga[2][2], gb[2][2];
  #pragma unroll
  for (int j = 0; j < 2; j++){
    int ci = w * 128 + j * 64 + lane;
    int rh = ci >> 3, s = ci & 7;
    int gk = (s ^ (rh & 7)) * 8;
    #pragma unroll
    for (int h = 0; h < 2; h++){
      ga[h][j] = (size_t)(m0 + h * 128 + rh) * K + gk;
      gb[h][j] = (size_t)(n0 + h * 128 + rh) * K + gk;
    }
  }
  const int nk = K >> 6;

  auto stA = [&](int buf, int h, int kt){
    #pragma unroll
    for (int j = 0; j < 2; j++)
      GLOAD16(A + ga[h][j] + (size_t)kt * 64, &lA[buf][h * 8192 + (w * 128 + j * 64) * 8]);
  };
  auto stB = [&](int buf, int h, int kt){
    #pragma unroll
    for (int j = 0; j < 2; j++)
      GLOAD16(Bt + gb[h][j] + (size_t)kt * 64, &lB[buf][h * 8192 + (w * 128 + j * 64) * 8]);
  };

  // prologue: tile0 {A0,B0,B1,A1}, tile1 {A0,B0,B1}; vmcnt(6) confirms tile0.
  stA(0, 0, 0); stB(0, 0, 0); stB(0, 1, 0); stA(0, 1, 0);
  stA(1, 0, 1); stB(1, 0, 1); stB(1, 1, 1);
  asm volatile("s_waitcnt vmcnt(6)" ::: "memory");
  BAR();

  f32x4 acc[8][4] = {};
  short8 a[4][2], b[4][2];

  for (int t = 0; t < nk; ++t){
    const int cur = t & 1;
    const u16* la = lA[cur];
    const u16* lb = lB[cur];

    // ---- phase 1: ds A0(8) + B0(4); stage A1(t+1); MFMA A0xB0
    #pragma unroll
    for (int f = 0; f < 4; f++){
      int r = f * 32 + wm * 16 + l15;
      #pragma unroll
      for (int ks = 0; ks < 2; ks++){
        int c = ks * 4 + l4;
        a[f][ks] = *(const short8*)&la[r * 64 + ((c ^ (r & 7)) * 8)];
      }
    }
    #pragma unroll
    for (int g = 0; g < 2; g++){
      int r = g * 64 + wn * 16 + l15;
      #pragma unroll
      for (int ks = 0; ks < 2; ks++){
        int c = ks * 4 + l4;
        b[g][ks] = *(const short8*)&lb[r * 64 + ((c ^ (r & 7)) * 8)];
      }
    }
    if (t + 1 < nk) stA(cur ^ 1, 1, t + 1);
    BAR();
    __builtin_amdgcn_s_setprio(1);
    #pragma unroll
    for (int f = 0; f < 4; f++)
      #pragma unroll
      for (int g = 0; g < 2; g++)
        #pragma unroll
        for (int ks = 0; ks < 2; ks++)
          acc[f][g] = __builtin_amdgcn_mfma_f32_16x16x32_bf16(a[f][ks], b[g][ks], acc[f][g], 0, 0, 0);
    __builtin_amdgcn_s_setprio(0);
    BAR();

    // ---- phase 2: ds B1(4); stage A0(t+2); MFMA A0xB1
    #pragma unroll
    for (int g = 2; g < 4; g++){
      int r = (g - 2) * 64 + wn * 16 + l15;
      #pragma unroll
      for (int ks = 0; ks < 2; ks++){
        int c = ks * 4 + l4;
        b[g][ks] = *(const short8*)&lb[8192 + r * 64 + ((c ^ (r & 7)) * 8)];
      }
    }
    if (t + 2 < nk) stA(cur, 0, t + 2);
    BAR();
    __builtin_amdgcn_s_setprio(1);
    #pragma unroll
    for (int f = 0; f < 4; f++)
      #pragma unroll
      for (int g = 2; g < 4; g++)
        #pragma unroll
        for (int ks = 0; ks < 2; ks++)
          acc[f][g] = __builtin_amdgcn_mfma_f32_16x16x32_bf16(a[f][ks], b[g][ks], acc[f][g], 0, 0, 0);
    __builtin_amdgcn_s_setprio(0);
    BAR();

    // ---- phase 3: ds A1(8); stage B0(t+2); MFMA A1xB1
    #pragma unroll
    for (int f = 0; f < 4; f++){
      int r = f * 32 + wm * 16 + l15;   // rows 128..255 live at lA[...][8192+]
      #pragma unroll
      for (int ks = 0; ks < 2; ks++){
        int c = ks * 4 + l4;
        a[f][ks] = *(const short8*)&la[8192 + r * 64 + ((c ^ (r & 7)) * 8)];
      }
    }
    if (t + 2 < nk) stB(cur, 0, t + 2);
    BAR();
    __builtin_amdgcn_s_setprio(1);
    #pragma unroll
    for (int f = 0; f < 4; f++)
      #pragma unroll
      for (int g = 2; g < 4; g++)
        #pragma unroll
        for (int ks = 0; ks < 2; ks++)
          acc[f + 4][g] = __builtin_amdgcn_mfma_f32_16x16x32_bf16(a[f][ks], b[g][ks], acc[f + 4][g], 0, 0, 0);
    __builtin_amdgcn_s_setprio(0);
    BAR();

    // ---- phase 4: stage B1(t+2); boundary vmcnt; MFMA A1xB0
    if (t + 2 < nk) stB(cur, 1, t + 2);
    if (t + 1 < nk){
      if (t + 2 < nk) asm volatile("s_waitcnt vmcnt(6)" ::: "memory");
      else            asm volatile("s_waitcnt vmcnt(0)" ::: "memory");
    }
    BAR();
    __builtin_amdgcn_s_setprio(1);
    #pragma unroll
    for (int f = 0; f < 4; f++)
      #pragma unroll
      for (int g = 0; g < 2; g++)
        #pragma unroll
        for (int ks = 0; ks < 2; ks++)
          acc[f + 4][g] = __builtin_amdgcn_mfma_f32_16x16x32_bf16(a[f][ks], b[g][ks], acc[f + 4][g], 0, 0, 0);
    __builtin_amdgcn_s_setprio(0);
    BAR();
  }

  // epilogue
  #pragma unroll
  for (int f = 0; f < 8; f++){
    #pragma unroll
    for (int g = 0; g < 4; g++){
      int col = n0 + g * 64 + wn * 16 + l15;
      float bv = HAS_BIAS ? bias[col] : 0.0f;
      #pragma unroll
      for (int j = 0; j < 4; j++){
        int row = m0 + f * 32 + wm * 16 + l4 * 4 + j;
        float v = acc[f][g][j] + bv;
        if (OUT_BF16) ((u16*)Cv)[(size_t)row * N + col] = f2b(v);
        else          ((float*)Cv)[(size_t)row * N + col] = v;
      }
    }
  }
}

// ---------------------------------------------------------------- fused smolgen
// hidden = LN256(silu(compressed @ sh1_wb + sh1_b))  [kept in LDS]
// gen    = LN4096(silu(hidden @ sg_wb + sg_b)) -> bf16
// 256 blocks x 512 threads, 2 batches/block, bf16 weights (halved L2 stream).
__global__ __launch_bounds__(512) void smol_fused(const u16* __restrict__ qkvb,
                                                  const u16* __restrict__ sh1_wb,
                                                  const float* __restrict__ sh1_b,
                                                  const float* __restrict__ ln1_g,
                                                  const float* __restrict__ ln1_b,
                                                  const u16* __restrict__ sg_wb,
                                                  const float* __restrict__ sg_b,
                                                  const float* __restrict__ ln2_g,
                                                  const float* __restrict__ ln2_b,
                                                  u16* __restrict__ genb){
  const int b0 = blockIdx.x * 2;
  const int tid = threadIdx.x;
  __shared__ u16 cb[2][2048];
  __shared__ float part[8][2][256];
  __shared__ float rs[32];
  __shared__ float hb[2][256];
  {
    int bi = tid >> 8, rem = tid & 255;
    int l = rem >> 2, cc = rem & 3;
    *(short8*)&cb[bi][rem * 8] =
        *(const short8*)&qkvb[(size_t)((b0 + bi) * 64 + l) * NQKV + 3072 + cc * 8];
  }
  __syncthreads();
  // ---- layer 1: 8-way K-split, bf16 weights
  {
    const int g = tid >> 6;          // k-group
    const int c4 = (tid & 63) * 4;   // cols c4..c4+3
    float4 a0 = {0,0,0,0}, a1 = {0,0,0,0};
    for (int kk2 = 0; kk2 < 256; kk2++){
      int k = g * 256 + kk2;
      ushort4 wv = *(const ushort4*)&sh1_wb[(size_t)k * 256 + c4];
      float w0 = b2f(wv.x), w1 = b2f(wv.y), w2 = b2f(wv.z), w3 = b2f(wv.w);
      float x0 = b2f(cb[0][k]), x1 = b2f(cb[1][k]);
      a0.x += x0 * w0; a0.y += x0 * w1; a0.z += x0 * w2; a0.w += x0 * w3;
      a1.x += x1 * w0; a1.y += x1 * w1; a1.z += x1 * w2; a1.w += x1 * w3;
    }
    *(float4*)&part[g][0][c4] = a0;
    *(float4*)&part[g][1][c4] = a1;
  }
  __syncthreads();
  {
    const int bi = tid >> 8, col = tid & 255;
    float y = sh1_b[col];
    #pragma unroll
    for (int g2 = 0; g2 < 8; g2++) y += part[g2][bi][col];
    y = y / (1.f + __expf(-y));
    float s = y, q = y * y;
    #pragma unroll
    for (int o = 32; o > 0; o >>= 1){ s += __shfl_down(s, o); q += __shfl_down(q, o); }
    int wv_ = tid >> 6;
    if ((tid & 63) == 0){ rs[wv_ * 2] = s; rs[wv_ * 2 + 1] = q; }
    __syncthreads();
    float S = 0, Q = 0;
    #pragma unroll
    for (int w2 = 0; w2 < 4; w2++){ S += rs[(bi * 4 + w2) * 2]; Q += rs[(bi * 4 + w2) * 2 + 1]; }
    float m = S * (1.f / 256.f), var = Q * (1.f / 256.f) - m * m;
    hb[bi][col] = (y - m) * rsqrtf(var + 1e-3f) * ln1_g[col] + ln1_b[col];
  }
  __syncthreads();
  // ---- layer 2: bf16 weights, 2 col-chunks/thread
  const int c4 = tid * 4;   // chunk0 col; chunk1 col = 2048 + c4
  float4 A00 = {0,0,0,0}, A01 = {0,0,0,0}, A10 = {0,0,0,0}, A11 = {0,0,0,0};
  for (int k = 0; k < 256; k++){
    float h0 = hb[0][k], h1 = hb[1][k];
    ushort4 u0 = *(const ushort4*)&sg_wb[(size_t)k * 4096 + c4];
    ushort4 u1 = *(const ushort4*)&sg_wb[(size_t)k * 4096 + 2048 + c4];
    float w00 = b2f(u0.x), w01 = b2f(u0.y), w02 = b2f(u0.z), w03 = b2f(u0.w);
    float w10 = b2f(u1.x), w11 = b2f(u1.y), w12 = b2f(u1.z), w13 = b2f(u1.w);
    A00.x += h0 * w00; A00.y += h0 * w01; A00.z += h0 * w02; A00.w += h0 * w03;
    A01.x += h0 * w10; A01.y += h0 * w11; A01.z += h0 * w12; A01.w += h0 * w13;
    A10.x += h1 * w00; A10.y += h1 * w01; A10.z += h1 * w02; A10.w += h1 * w03;
    A11.x += h1 * w10; A11.y += h1 * w11; A11.z += h1 * w12; A11.w += h1 * w13;
  }
  float4 b0v = *(const float4*)&sg_b[c4];
  float4 b1v = *(const float4*)&sg_b[2048 + c4];
  float s0 = 0, q0 = 0, s1 = 0, q1 = 0;
  float* p;
  #pragma unroll
  for (int e = 0; e < 4; e++){
    p = (float*)&A00; float y = p[e] + ((float*)&b0v)[e]; y = y / (1.f + __expf(-y)); p[e] = y; s0 += y; q0 += y * y;
    p = (float*)&A01; y = p[e] + ((float*)&b1v)[e]; y = y / (1.f + __expf(-y)); p[e] = y; s0 += y; q0 += y * y;
    p = (float*)&A10; y = p[e] + ((float*)&b0v)[e]; y = y / (1.f + __expf(-y)); p[e] = y; s1 += y; q1 += y * y;
    p = (float*)&A11; y = p[e] + ((float*)&b1v)[e]; y = y / (1.f + __expf(-y)); p[e] = y; s1 += y; q1 += y * y;
  }
  #pragma unroll
  for (int o = 32; o > 0; o >>= 1){
    s0 += __shfl_down(s0, o); q0 += __shfl_down(q0, o);
    s1 += __shfl_down(s1, o); q1 += __shfl_down(q1, o);
  }
  int wv_ = tid >> 6;
  __syncthreads();   // rs reuse: layer-1 reads done
  if ((tid & 63) == 0){ rs[wv_ * 4] = s0; rs[wv_ * 4 + 1] = q0; rs[wv_ * 4 + 2] = s1; rs[wv_ * 4 + 3] = q1; }
  __syncthreads();
  float S0 = 0, Q0 = 0, S1 = 0, Q1 = 0;
  #pragma unroll
  for (int w2 = 0; w2 < 8; w2++){
    S0 += rs[w2 * 4]; Q0 += rs[w2 * 4 + 1]; S1 += rs[w2 * 4 + 2]; Q1 += rs[w2 * 4 + 3];
  }
  float m0 = S0 * (1.f / 4096.f), v0 = Q0 * (1.f / 4096.f) - m0 * m0;
  float m1 = S1 * (1.f / 4096.f), v1 = Q1 * (1.f / 4096.f) - m1 * m1;
  float is0 = rsqrtf(v0 + 1e-3f), is1 = rsqrtf(v1 + 1e-3f);
  float4 g0 = *(const float4*)&ln2_g[c4],        gb0 = *(const float4*)&ln2_b[c4];
  float4 g1 = *(const float4*)&ln2_g[2048 + c4], gb1 = *(const float4*)&ln2_b[2048 + c4];
  float4 o00, o01, o10, o11;
  #pragma unroll
  for (int e = 0; e < 4; e++){
    ((float*)&o00)[e] = (((float*)&A00)[e] - m0) * is0 * ((float*)&g0)[e] + ((float*)&gb0)[e];
    ((float*)&o01)[e] = (((float*)&A01)[e] - m0) * is0 * ((float*)&g1)[e] + ((float*)&gb1)[e];
    ((float*)&o10)[e] = (((float*)&A10)[e] - m1) * is1 * ((float*)&g0)[e] + ((float*)&gb0)[e];
    ((float*)&o11)[e] = (((float*)&A11)[e] - m1) * is1 * ((float*)&g1)[e] + ((float*)&gb1)[e];
  }
  *(uint2*)&genb[(size_t)(b0    ) * 4096 + c4]        = pack4(o00);
  *(uint2*)&genb[(size_t)(b0    ) * 4096 + 2048 + c4] = pack4(o01);
  *(uint2*)&genb[(size_t)(b0 + 1) * 4096 + c4]        = pack4(o10);
  *(uint2*)&genb[(size_t)(b0 + 1) * 4096 + 2048 + c4] = pack4(o11);
}

// ---------------------------------------------------------------- fused attention
// Wave-complete rows (R10: part of the 807->782 pair). q/k staging now via
// global_load_lds (pre-swizzled per-lane source, linear LDS dest — gemm pattern);
// v transpose stays VALU. __syncthreads supplies the vmcnt drain.
__global__ __launch_bounds__(256) void attn_fused(const u16* __restrict__ qkvb,
                                                  const u16* __restrict__ smolb,
                                                  u16* __restrict__ aout){
  const int bh = blockIdx.x;
  const int b = bh >> 4, h = bh & 15;
  __shared__ u16 qs[4096], kts[4096], vts[4096], ps[4096];
  const int tid = threadIdx.x, w = tid >> 6, lane = tid & 63;
  const int l15 = lane & 15, g = lane >> 4;

  const u16* qb = qkvb + (size_t)(b * 64) * NQKV + h * 64;
  const u16* kb = qb + 1024;
  const u16* vb = qb + 2048;

  // q/k: 2 GLOAD16 each per wave; LDS chunk (r,s) holds global chunk s^(r&7)
  {
    int ci = w * 128 + lane;
    int r = ci >> 3, s = ci & 7;
    const u16* qsrc = qb + (size_t)r * NQKV + (s ^ (r & 7)) * 8;
    const u16* ksrc = kb + (size_t)r * NQKV + (s ^ (r & 7)) * 8;
    GLOAD16(qsrc,                    &qs [(w * 128) * 8]);
    GLOAD16(qsrc + (size_t)8 * NQKV, &qs [(w * 128 + 64) * 8]);
    GLOAD16(ksrc,                    &kts[(w * 128) * 8]);
    GLOAD16(ksrc + (size_t)8 * NQKV, &kts[(w * 128 + 64) * 8]);
  }
  // v^T via VALU transpose
  #pragma unroll
  for (int i = 0; i < 2; i++){
    int c = i * 256 + tid;
    int r = c >> 3, cc = c & 7;
    short8 vv = *(const short8*)&vb[(size_t)r * NQKV + cc * 8];
    #pragma unroll
    for (int j = 0; j < 8; j++){
      int hd = cc * 8 + j;
      int pcv = (r >> 3) ^ (hd & 7);
      vts[hd * 64 + pcv * 8 + (r & 7)] = (u16)vv[j];
    }
  }
  __syncthreads();

  // QK^T: wave w -> rows w*16..w*16+15, all 64 cols (4 fn frags)
  f32x4 sacc[4] = {};
  #pragma unroll
  for (int ksi = 0; ksi < 2; ksi++){
    int ra = w * 16 + l15;
    int ca = ksi * 4 + g;
    short8 af = *(const short8*)&qs[ra * 64 + ((ca ^ (ra & 7)) * 8)];
    #pragma unroll
    for (int fn = 0; fn < 4; fn++){
      int rb = fn * 16 + l15;
      short8 bf = *(const short8*)&kts[rb * 64 + ((ca ^ (rb & 7)) * 8)];
      sacc[fn] = __builtin_amdgcn_mfma_f32_16x16x32_bf16(af, bf, sacc[fn], 0, 0, 0);
    }
  }

  // in-register softmax over rows q = w*16 + g*4 + j
  const u16* sm = smolb + (size_t)bh * 4096;
  float vals[4][4];     // [fn][j]
  float mx[4] = {-3.4e38f, -3.4e38f, -3.4e38f, -3.4e38f};
  #pragma unroll
  for (int fn = 0; fn < 4; fn++)
    #pragma unroll
    for (int j = 0; j < 4; j++){
      int q = w * 16 + g * 4 + j;
      float v = sacc[fn][j] * 0.125f + b2f(sm[q * 64 + fn * 16 + l15]);
      vals[fn][j] = v;
      mx[j] = fmaxf(mx[j], v);
    }
  #pragma unroll
  for (int o = 1; o < 16; o <<= 1)
    #pragma unroll
    for (int j = 0; j < 4; j++) mx[j] = fmaxf(mx[j], __shfl_xor(mx[j], o));
  float sum[4] = {0, 0, 0, 0};
  #pragma unroll
  for (int fn = 0; fn < 4; fn++)
    #pragma unroll
    for (int j = 0; j < 4; j++){
      vals[fn][j] = __expf(vals[fn][j] - mx[j]);
      sum[j] += vals[fn][j];
    }
  #pragma unroll
  for (int o = 1; o < 16; o <<= 1)
    #pragma unroll
    for (int j = 0; j < 4; j++) sum[j] += __shfl_xor(sum[j], o);
  float rinv[4];
  #pragma unroll
  for (int j = 0; j < 4; j++) rinv[j] = 1.f / sum[j];

  // write P (bf16) to ps, chunk-swizzled row-major
  #pragma unroll
  for (int fn = 0; fn < 4; fn++)
    #pragma unroll
    for (int j = 0; j < 4; j++){
      int q = w * 16 + g * 4 + j;
      int c = fn * 16 + l15;
      int cs = (c & 7) | ((((c >> 3) ^ (q & 7)) & 7) << 3);
      ps[q * 64 + cs] = f2b(vals[fn][j] * rinv[j]);
    }
  __syncthreads();

  // O = P @ V : wave w -> rows w*16..+15, all 64 hd
  f32x4 oacc[4] = {};
  #pragma unroll
  for (int ksi = 0; ksi < 2; ksi++){
    int ra = w * 16 + l15;
    int ca = ksi * 4 + g;
    short8 af = *(const short8*)&ps[ra * 64 + ((ca ^ (ra & 7)) * 8)];
    #pragma unroll
    for (int fn = 0; fn < 4; fn++){
      int rb = fn * 16 + l15;
      short8 bf = *(const short8*)&vts[rb * 64 + ((ca ^ (rb & 7)) * 8)];
      oacc[fn] = __builtin_amdgcn_mfma_f32_16x16x32_bf16(af, bf, oacc[fn], 0, 0, 0);
    }
  }
  #pragma unroll
  for (int fn = 0; fn < 4; fn++)
    #pragma unroll
    for (int j = 0; j < 4; j++){
      int q  = w * 16 + g * 4 + j;
      int hd = fn * 16 + l15;
      aout[(size_t)(b * 64 + q) * 1024 + h * 64 + hd] = f2b(oacc[fn][j]);
    }
}

// ---------------------------------------------------------------- launcher
extern "C" void kernel_launch(void* const* d_in, const int* in_sizes, int n_in,
                              void* d_out, int out_size, void* d_ws, size_t ws_size,
                              hipStream_t stream){
  const float* x     = (const float*)d_in[0];
  const float* wq    = (const float*)d_in[1];
  const float* bq    = (const float*)d_in[2];
  const float* wk    = (const float*)d_in[3];
  const float* bk    = (const float*)d_in[4];
  const float* wv    = (const float*)d_in[5];
  const float* bv    = (const float*)d_in[6];
  const float* wo    = (const float*)d_in[7];
  const float* bo    = (const float*)d_in[8];
  const float* sc_w  = (const float*)d_in[9];
  const float* sh1_w = (const float*)d_in[10];
  const float* sh1_b = (const float*)d_in[11];
  const float* ln1_g = (const float*)d_in[12];
  const float* ln1_b = (const float*)d_in[13];
  const float* sg_w  = (const float*)d_in[14];
  const float* sg_b  = (const float*)d_in[15];
  const float* ln2_g = (const float*)d_in[16];
  const float* ln2_b = (const float*)d_in[17];
  const float* swg_w = (const float*)d_in[18];

  char* ws = (char*)d_ws;
  size_t off = 0;
  auto alloc = [&](size_t bytes){ void* p = ws + off; off += (bytes + 255) & ~(size_t)255; return p; };
  u16*   xb     = (u16*)  alloc((size_t)MROWS * EMB * 2);
  u16*   wqkvT  = (u16*)  alloc((size_t)NQKV * EMB * 2);
  float* qbias  = (float*)alloc((size_t)NQKV * 4);
  u16*   woT    = (u16*)  alloc((size_t)1024 * 1024 * 2);
  u16*   swgT   = (u16*)  alloc((size_t)4096 * 256 * 2);
  u16*   sh1_wb = (u16*)  alloc((size_t)2048 * 256 * 2);
  u16*   sg_wb  = (u16*)  alloc((size_t)256 * 4096 * 2);
  u16*   qkvb   = (u16*)  alloc((size_t)MROWS * NQKV * 2);
  u16*   genb   = (u16*)  alloc((size_t)512 * 4096 * 2);
  u16*   smolb  = (u16*)  alloc((size_t)8192 * 4096 * 2);   // bf16 logit bias
  u16*   aout   = (u16*)  alloc((size_t)MROWS * 1024 * 2);

  // --- single fused prep: x->bf16, weight transposes/conversions, pad, bias ---
  prep_all<<<PREP_BLOCKS, 256, 0, stream>>>(x, xb, wq, wk, wv, sc_w, wo, swg_w,
                                            wqkvT, woT, swgT, bq, bk, bv, qbias,
                                            sh1_w, sh1_wb, sg_w, sg_wb);

  // --- fused QKV + compressed projection: [32768,1024] @ [1024,3328] ---
  gemm256<1, 1><<<(MROWS / 256) * (NQKV / 256), 512, 0, stream>>>(
      xb, wqkvT, qbias, qkvb, MROWS, NQKV, 1024);

  // --- fused smolgen chain (hidden + gen, bf16 weights) ---
  smol_fused<<<BATCH / 2, 512, 0, stream>>>(qkvb, sh1_wb, sh1_b, ln1_g, ln1_b,
                                            sg_wb, sg_b, ln2_g, ln2_b, genb);
  gemm256<1, 0><<<(8192 / 256) * (4096 / 256), 512, 0, stream>>>(
      genb, swgT, nullptr, smolb, 8192, 4096, 256);

  // --- attention ---
  attn_fused<<<BATCH * NH, 256, 0, stream>>>(qkvb, smolb, aout);

  // --- output projection: [32768,1024] @ [1024,1024] + bo -> fp32 d_out ---
  gemm256<0, 1><<<(MROWS / 256) * (1024 / 256), 512, 0, stream>>>(
      aout, woT, bo, d_out, MROWS, 1024, 1024);
}